// Round 1
// baseline (1025.175 us; speedup 1.0000x reference)
//
#include <hip/hip_runtime.h>
#include <math.h>

// ---------------------------------------------------------------------------
// Problem constants (from reference)
//   nh [N,128] f32, eh [E,16] f32, edge_index [2,E] i32,
//   W1 [128,256], b1[256], W2 [256,128], b2[128]
//   out = concat( n_h + nz  [N,128],  eh [E,16] )
// ---------------------------------------------------------------------------

#define D_IN   128
#define D_HID  256
#define D_OUT  128

// ---------------------------------------------------------------------------
// Generic fp32 GEMM: C = act(A[M,K] @ B[K,N] + bias), optional second output.
// 64x64 tile, 256 threads, 4x4 micro-tile per thread, BK=16.
// N must be a multiple of 64, K a multiple of 16. M is guarded.
// ---------------------------------------------------------------------------
__global__ __launch_bounds__(256)
void gemm_bias_act(const float* __restrict__ A,
                   const float* __restrict__ B,
                   const float* __restrict__ bias,
                   float* __restrict__ C,
                   float* __restrict__ C2,
                   int M, int N, int K, int do_relu)
{
    __shared__ float As[16][65];
    __shared__ float Bs[16][65];

    const int tid = threadIdx.x;
    const int tx = tid & 15;        // output col group
    const int ty = tid >> 4;        // output row group
    const int brow = blockIdx.y * 64;
    const int bcol = blockIdx.x * 64;

    // A-tile load mapping: 64 rows x 16 k, float4 per thread
    const int arow  = tid >> 2;          // 0..63
    const int acol  = (tid & 3) * 4;     // 0,4,8,12
    // B-tile load mapping: 16 k x 64 cols, float4 per thread
    const int bkrow = tid >> 4;          // 0..15
    const int bncol = (tid & 15) * 4;    // 0..60

    float acc[4][4];
#pragma unroll
    for (int i = 0; i < 4; ++i)
#pragma unroll
        for (int j = 0; j < 4; ++j) acc[i][j] = 0.f;

    for (int k0 = 0; k0 < K; k0 += 16) {
        float4 av = make_float4(0.f, 0.f, 0.f, 0.f);
        if (brow + arow < M)
            av = *(const float4*)(A + (size_t)(brow + arow) * K + k0 + acol);
        As[acol + 0][arow] = av.x;
        As[acol + 1][arow] = av.y;
        As[acol + 2][arow] = av.z;
        As[acol + 3][arow] = av.w;

        float4 bv = *(const float4*)(B + (size_t)(k0 + bkrow) * N + bcol + bncol);
        Bs[bkrow][bncol + 0] = bv.x;
        Bs[bkrow][bncol + 1] = bv.y;
        Bs[bkrow][bncol + 2] = bv.z;
        Bs[bkrow][bncol + 3] = bv.w;

        __syncthreads();

#pragma unroll
        for (int kk = 0; kk < 16; ++kk) {
            float a0 = As[kk][ty * 4 + 0];
            float a1 = As[kk][ty * 4 + 1];
            float a2 = As[kk][ty * 4 + 2];
            float a3 = As[kk][ty * 4 + 3];
            float b0 = Bs[kk][tx * 4 + 0];
            float b1 = Bs[kk][tx * 4 + 1];
            float b2 = Bs[kk][tx * 4 + 2];
            float b3 = Bs[kk][tx * 4 + 3];
            acc[0][0] = fmaf(a0, b0, acc[0][0]);
            acc[0][1] = fmaf(a0, b1, acc[0][1]);
            acc[0][2] = fmaf(a0, b2, acc[0][2]);
            acc[0][3] = fmaf(a0, b3, acc[0][3]);
            acc[1][0] = fmaf(a1, b0, acc[1][0]);
            acc[1][1] = fmaf(a1, b1, acc[1][1]);
            acc[1][2] = fmaf(a1, b2, acc[1][2]);
            acc[1][3] = fmaf(a1, b3, acc[1][3]);
            acc[2][0] = fmaf(a2, b0, acc[2][0]);
            acc[2][1] = fmaf(a2, b1, acc[2][1]);
            acc[2][2] = fmaf(a2, b2, acc[2][2]);
            acc[2][3] = fmaf(a2, b3, acc[2][3]);
            acc[3][0] = fmaf(a3, b0, acc[3][0]);
            acc[3][1] = fmaf(a3, b1, acc[3][1]);
            acc[3][2] = fmaf(a3, b2, acc[3][2]);
            acc[3][3] = fmaf(a3, b3, acc[3][3]);
        }
        __syncthreads();
    }

#pragma unroll
    for (int i = 0; i < 4; ++i) {
        int row = brow + ty * 4 + i;
        if (row >= M) continue;
        int col = bcol + tx * 4;
        float4 v;
        v.x = acc[i][0] + bias[col + 0];
        v.y = acc[i][1] + bias[col + 1];
        v.z = acc[i][2] + bias[col + 2];
        v.w = acc[i][3] + bias[col + 3];
        if (do_relu) {
            v.x = fmaxf(v.x, 0.f); v.y = fmaxf(v.y, 0.f);
            v.z = fmaxf(v.z, 0.f); v.w = fmaxf(v.w, 0.f);
        }
        *(float4*)(C + (size_t)row * N + col) = v;
        if (C2) *(float4*)(C2 + (size_t)row * N + col) = v;
    }
}

// ---------------------------------------------------------------------------
// init segmax (ordered-uint encoding of float, 0 == "less than -inf") / denom
// ---------------------------------------------------------------------------
__global__ void init_seg(unsigned int* __restrict__ segmax,
                         float* __restrict__ denom, int n)
{
    int i = blockIdx.x * blockDim.x + threadIdx.x;
    if (i < n) { segmax[i] = 0u; denom[i] = 0.f; }
}

__device__ __forceinline__ unsigned int f2key(float f)
{
    unsigned int b = __float_as_uint(f);
    return (b & 0x80000000u) ? ~b : (b | 0x80000000u);
}
__device__ __forceinline__ float key2f(unsigned int k)
{
    unsigned int b = (k & 0x80000000u) ? (k & 0x7FFFFFFFu) : ~k;
    return __uint_as_float(b);
}

// ---------------------------------------------------------------------------
// Wave-per-edge attention score: attn[e] = dot(n_h[src], n_h[dst]) (128 dims)
// ---------------------------------------------------------------------------
__global__ __launch_bounds__(256)
void edge_attn(const float* __restrict__ nh,
               const int* __restrict__ src, const int* __restrict__ dst,
               float* __restrict__ attn, unsigned int* __restrict__ segmax,
               int E)
{
    int wid  = (blockIdx.x * blockDim.x + threadIdx.x) >> 6;
    int lane = threadIdx.x & 63;
    if (wid >= E) return;
    int s = src[wid], d = dst[wid];
    float2 a = *(const float2*)(nh + (size_t)s * D_OUT + lane * 2);
    float2 b = *(const float2*)(nh + (size_t)d * D_OUT + lane * 2);
    float v = a.x * b.x + a.y * b.y;
#pragma unroll
    for (int off = 32; off > 0; off >>= 1) v += __shfl_xor(v, off);
    if (lane == 0) {
        attn[wid] = v;
        atomicMax(segmax + d, f2key(v));
    }
}

// ---------------------------------------------------------------------------
// Thread-per-edge: e = exp(attn - segmax[dst]); denom[dst] += e
// ---------------------------------------------------------------------------
__global__ __launch_bounds__(256)
void edge_exp(const float* __restrict__ attn, const int* __restrict__ dst,
              const unsigned int* __restrict__ segmax,
              float* __restrict__ eexp, float* __restrict__ denom, int E)
{
    int e = blockIdx.x * blockDim.x + threadIdx.x;
    if (e >= E) return;
    int d = dst[e];
    float m = key2f(segmax[d]);
    float v = expf(attn[e] - m);
    eexp[e] = v;
    atomicAdd(denom + d, v);
}

// ---------------------------------------------------------------------------
// Wave-per-edge weighted scatter: out[dst,:] += (e/denom[dst]) * n_h[src,:]
// ---------------------------------------------------------------------------
__global__ __launch_bounds__(256)
void edge_scatter(const float* __restrict__ nh,
                  const float* __restrict__ eexp, const float* __restrict__ denom,
                  const int* __restrict__ src, const int* __restrict__ dst,
                  float* __restrict__ out, int E)
{
    int wid  = (blockIdx.x * blockDim.x + threadIdx.x) >> 6;
    int lane = threadIdx.x & 63;
    if (wid >= E) return;
    int s = src[wid], d = dst[wid];
    float w = eexp[wid] / denom[d];
    float2 a = *(const float2*)(nh + (size_t)s * D_OUT + lane * 2);
    float* po = out + (size_t)d * D_OUT + lane * 2;
    atomicAdd(po + 0, w * a.x);
    atomicAdd(po + 1, w * a.y);
}

// ---------------------------------------------------------------------------
// float4 grid-stride copy (eh passthrough)
// ---------------------------------------------------------------------------
__global__ __launch_bounds__(256)
void copy_f4(const float4* __restrict__ in, float4* __restrict__ out, int n4)
{
    int i = blockIdx.x * blockDim.x + threadIdx.x;
    int stride = gridDim.x * blockDim.x;
    for (; i < n4; i += stride) out[i] = in[i];
}

// ---------------------------------------------------------------------------
extern "C" void kernel_launch(void* const* d_in, const int* in_sizes, int n_in,
                              void* d_out, int out_size, void* d_ws, size_t ws_size,
                              hipStream_t stream)
{
    const float* nh  = (const float*)d_in[0];
    const float* eh  = (const float*)d_in[1];
    const int*   ei  = (const int*)d_in[2];
    const float* W1  = (const float*)d_in[3];
    const float* b1  = (const float*)d_in[4];
    const float* W2  = (const float*)d_in[5];
    const float* b2  = (const float*)d_in[6];

    const int N = in_sizes[0] / D_IN;        // 50000
    const int E = in_sizes[2] / 2;           // 800000
    const int EH = in_sizes[1];              // 12.8M floats

    const int* src = ei;
    const int* dst = ei + E;

    float* out_nh = (float*)d_out;                       // [N,128]
    float* out_eh = (float*)d_out + (size_t)N * D_OUT;   // [E,16]

    // Workspace layout (bytes):
    //   region A [0 .. N*D_HID*4): h1 during MLP; re-used afterwards for edge bufs
    //   region B: n_h [N*D_OUT floats]
    char* ws = (char*)d_ws;
    float* h1   = (float*)ws;                                     // N*256 f32
    float* n_h  = (float*)(ws + (size_t)N * D_HID * 4);           // N*128 f32
    // After gemm2 completes, alias edge buffers into region A:
    float*        attn   = (float*)ws;                            // E f32
    float*        eexp   = (float*)(ws + (size_t)E * 4);          // E f32
    unsigned int* segmax = (unsigned int*)(ws + (size_t)E * 8);   // N u32
    float*        denom  = (float*)(ws + (size_t)E * 8 + (size_t)N * 4); // N f32

    // 1) h1 = relu(nh @ W1 + b1)
    {
        dim3 grid(D_HID / 64, (N + 63) / 64);
        gemm_bias_act<<<grid, 256, 0, stream>>>(nh, W1, b1, h1, nullptr,
                                                N, D_HID, D_IN, 1);
    }
    // 2) n_h = h1 @ W2 + b2  (also initializes out_nh = n_h)
    {
        dim3 grid(D_OUT / 64, (N + 63) / 64);
        gemm_bias_act<<<grid, 256, 0, stream>>>(h1, W2, b2, n_h, out_nh,
                                                N, D_OUT, D_HID, 0);
    }
    // 3) init segmax/denom (after gemm2 — they alias h1's region)
    init_seg<<<(N + 255) / 256, 256, 0, stream>>>(segmax, denom, N);

    // 4) per-edge attention scores + segment max
    {
        int blocks = (E + 3) / 4;   // 4 waves (edges) per 256-thread block
        edge_attn<<<blocks, 256, 0, stream>>>(n_h, src, dst, attn, segmax, E);
    }
    // 5) exp + segment sum
    edge_exp<<<(E + 255) / 256, 256, 0, stream>>>(attn, dst, segmax, eexp, denom, E);

    // 6) weighted scatter-add into out
    {
        int blocks = (E + 3) / 4;
        edge_scatter<<<blocks, 256, 0, stream>>>(n_h, eexp, denom, src, dst,
                                                 out_nh, E);
    }
    // 7) eh passthrough
    copy_f4<<<2048, 256, 0, stream>>>((const float4*)eh, (float4*)out_eh, EH / 4);
}

// Round 2
// 466.698 us; speedup vs baseline: 2.1967x; 2.1967x over previous
//
#include <hip/hip_runtime.h>
#include <math.h>

// ---------------------------------------------------------------------------
// GAT layer:
//   n_h = relu(nh@W1+b1)@W2+b2
//   attn[e] = dot(n_h[src], n_h[dst]); segment-softmax over dst; 
//   out0 = n_h + segsum(attn * n_h[src]); out1 = eh
// Strategy: bucket edges by dst, then one wave per dst node does an online
// (flash-style) softmax + weighted accumulate fully in registers. No float
// atomics anywhere.
// ---------------------------------------------------------------------------

#define D_IN   128
#define D_HID  256
#define D_OUT  128

// ---------------------------------------------------------------------------
// fp32 GEMM: C = act(A[M,K] @ B[K,N] + bias). 64x64 tile, 256 thr, 4x4 micro.
// ---------------------------------------------------------------------------
__global__ __launch_bounds__(256)
void gemm_bias_act(const float* __restrict__ A,
                   const float* __restrict__ B,
                   const float* __restrict__ bias,
                   float* __restrict__ C,
                   int M, int N, int K, int do_relu)
{
    __shared__ float As[16][65];
    __shared__ float Bs[16][65];

    const int tid = threadIdx.x;
    const int tx = tid & 15;
    const int ty = tid >> 4;
    const int brow = blockIdx.y * 64;
    const int bcol = blockIdx.x * 64;

    const int arow  = tid >> 2;
    const int acol  = (tid & 3) * 4;
    const int bkrow = tid >> 4;
    const int bncol = (tid & 15) * 4;

    float acc[4][4];
#pragma unroll
    for (int i = 0; i < 4; ++i)
#pragma unroll
        for (int j = 0; j < 4; ++j) acc[i][j] = 0.f;

    for (int k0 = 0; k0 < K; k0 += 16) {
        float4 av = make_float4(0.f, 0.f, 0.f, 0.f);
        if (brow + arow < M)
            av = *(const float4*)(A + (size_t)(brow + arow) * K + k0 + acol);
        As[acol + 0][arow] = av.x;
        As[acol + 1][arow] = av.y;
        As[acol + 2][arow] = av.z;
        As[acol + 3][arow] = av.w;

        float4 bv = *(const float4*)(B + (size_t)(k0 + bkrow) * N + bcol + bncol);
        Bs[bkrow][bncol + 0] = bv.x;
        Bs[bkrow][bncol + 1] = bv.y;
        Bs[bkrow][bncol + 2] = bv.z;
        Bs[bkrow][bncol + 3] = bv.w;

        __syncthreads();

#pragma unroll
        for (int kk = 0; kk < 16; ++kk) {
            float a0 = As[kk][ty * 4 + 0];
            float a1 = As[kk][ty * 4 + 1];
            float a2 = As[kk][ty * 4 + 2];
            float a3 = As[kk][ty * 4 + 3];
            float b0 = Bs[kk][tx * 4 + 0];
            float b1 = Bs[kk][tx * 4 + 1];
            float b2 = Bs[kk][tx * 4 + 2];
            float b3 = Bs[kk][tx * 4 + 3];
            acc[0][0] = fmaf(a0, b0, acc[0][0]);
            acc[0][1] = fmaf(a0, b1, acc[0][1]);
            acc[0][2] = fmaf(a0, b2, acc[0][2]);
            acc[0][3] = fmaf(a0, b3, acc[0][3]);
            acc[1][0] = fmaf(a1, b0, acc[1][0]);
            acc[1][1] = fmaf(a1, b1, acc[1][1]);
            acc[1][2] = fmaf(a1, b2, acc[1][2]);
            acc[1][3] = fmaf(a1, b3, acc[1][3]);
            acc[2][0] = fmaf(a2, b0, acc[2][0]);
            acc[2][1] = fmaf(a2, b1, acc[2][1]);
            acc[2][2] = fmaf(a2, b2, acc[2][2]);
            acc[2][3] = fmaf(a2, b3, acc[2][3]);
            acc[3][0] = fmaf(a3, b0, acc[3][0]);
            acc[3][1] = fmaf(a3, b1, acc[3][1]);
            acc[3][2] = fmaf(a3, b2, acc[3][2]);
            acc[3][3] = fmaf(a3, b3, acc[3][3]);
        }
        __syncthreads();
    }

#pragma unroll
    for (int i = 0; i < 4; ++i) {
        int row = brow + ty * 4 + i;
        if (row >= M) continue;
        int col = bcol + tx * 4;
        float4 v;
        v.x = acc[i][0] + bias[col + 0];
        v.y = acc[i][1] + bias[col + 1];
        v.z = acc[i][2] + bias[col + 2];
        v.w = acc[i][3] + bias[col + 3];
        if (do_relu) {
            v.x = fmaxf(v.x, 0.f); v.y = fmaxf(v.y, 0.f);
            v.z = fmaxf(v.z, 0.f); v.w = fmaxf(v.w, 0.f);
        }
        *(float4*)(C + (size_t)row * N + col) = v;
    }
}

// ---------------------------------------------------------------------------
// zero two uint buffers
// ---------------------------------------------------------------------------
__global__ void zero2(unsigned int* __restrict__ a, unsigned int* __restrict__ b,
                      int n)
{
    int i = blockIdx.x * blockDim.x + threadIdx.x;
    if (i < n) { a[i] = 0u; b[i] = 0u; }
}

// ---------------------------------------------------------------------------
// histogram of dst
// ---------------------------------------------------------------------------
__global__ __launch_bounds__(256)
void hist_dst(const int* __restrict__ dst, unsigned int* __restrict__ count, int E)
{
    int e = blockIdx.x * blockDim.x + threadIdx.x;
    if (e < E) atomicAdd(count + dst[e], 1u);
}

// ---------------------------------------------------------------------------
// single-block exclusive scan of count[0..n) -> off[0..n], off[n]=total
// 1024 threads, each owns a contiguous chunk.
// ---------------------------------------------------------------------------
__global__ __launch_bounds__(1024)
void scan_block(const unsigned int* __restrict__ count,
                unsigned int* __restrict__ off, int n)
{
    __shared__ unsigned int lds[1024];
    const int tid = threadIdx.x;
    const int CH = (n + 1023) / 1024;
    const int lo = tid * CH;
    const int hi = min(lo + CH, n);

    unsigned int s = 0;
    for (int j = lo; j < hi; ++j) s += count[j];
    lds[tid] = s;
    __syncthreads();

    // inclusive Hillis-Steele scan over 1024 partials
    for (int d = 1; d < 1024; d <<= 1) {
        unsigned int v = lds[tid];
        unsigned int add = (tid >= d) ? lds[tid - d] : 0u;
        __syncthreads();
        lds[tid] = v + add;
        __syncthreads();
    }

    unsigned int base = lds[tid] - s;   // exclusive base for this chunk
    unsigned int run = base;
    for (int j = lo; j < hi; ++j) { off[j] = run; run += count[j]; }
    if (tid == 1023) off[n] = lds[1023];
}

// ---------------------------------------------------------------------------
// fill sorted edge-id list: sorted[off[dst]+pos] = e
// ---------------------------------------------------------------------------
__global__ __launch_bounds__(256)
void fill_sorted(const int* __restrict__ dst, const unsigned int* __restrict__ off,
                 unsigned int* __restrict__ cursor, unsigned int* __restrict__ sorted,
                 int E)
{
    int e = blockIdx.x * blockDim.x + threadIdx.x;
    if (e >= E) return;
    int d = dst[e];
    unsigned int pos = atomicAdd(cursor + d, 1u);
    sorted[off[d] + pos] = (unsigned int)e;
}

// ---------------------------------------------------------------------------
// One wave per dst node: online softmax over incident edges, fused
// dot + exp + weighted accumulate. out[n] = n_h[n] + acc/denom.
// ---------------------------------------------------------------------------
__global__ __launch_bounds__(256)
void node_aggregate(const float* __restrict__ n_h,
                    const unsigned int* __restrict__ off,
                    const unsigned int* __restrict__ sorted,
                    const int* __restrict__ src,
                    float* __restrict__ out, int N)
{
    int wid  = (blockIdx.x * blockDim.x + threadIdx.x) >> 6;
    int lane = threadIdx.x & 63;
    if (wid >= N) return;

    const unsigned int beg = off[wid];
    const unsigned int end = off[wid + 1];

    float2 self = *(const float2*)(n_h + (size_t)wid * D_OUT + lane * 2);

    float m = -INFINITY;
    float denom = 0.f;
    float accx = 0.f, accy = 0.f;

    for (unsigned int i = beg; i < end; ++i) {
        unsigned int e = sorted[i];          // broadcast load
        int s = src[e];                      // broadcast load
        float2 a = *(const float2*)(n_h + (size_t)s * D_OUT + lane * 2);
        float p = a.x * self.x + a.y * self.y;
#pragma unroll
        for (int o = 32; o > 0; o >>= 1) p += __shfl_xor(p, o);
        float mnew = fmaxf(m, p);
        float scale = __expf(m - mnew);      // 0 on first iter (m=-inf)
        float w = __expf(p - mnew);
        denom = denom * scale + w;
        accx  = accx * scale + w * a.x;
        accy  = accy * scale + w * a.y;
        m = mnew;
    }

    float inv = (denom > 0.f) ? 1.f / denom : 0.f;
    float2 o;
    o.x = self.x + accx * inv;
    o.y = self.y + accy * inv;
    *(float2*)(out + (size_t)wid * D_OUT + lane * 2) = o;
}

// ---------------------------------------------------------------------------
// float4 grid-stride copy (eh passthrough)
// ---------------------------------------------------------------------------
__global__ __launch_bounds__(256)
void copy_f4(const float4* __restrict__ in, float4* __restrict__ out, int n4)
{
    int i = blockIdx.x * blockDim.x + threadIdx.x;
    int stride = gridDim.x * blockDim.x;
    for (; i < n4; i += stride) out[i] = in[i];
}

// ---------------------------------------------------------------------------
extern "C" void kernel_launch(void* const* d_in, const int* in_sizes, int n_in,
                              void* d_out, int out_size, void* d_ws, size_t ws_size,
                              hipStream_t stream)
{
    const float* nh  = (const float*)d_in[0];
    const float* eh  = (const float*)d_in[1];
    const int*   ei  = (const int*)d_in[2];
    const float* W1  = (const float*)d_in[3];
    const float* b1  = (const float*)d_in[4];
    const float* W2  = (const float*)d_in[5];
    const float* b2  = (const float*)d_in[6];

    const int N  = in_sizes[0] / D_IN;        // 50000
    const int E  = in_sizes[2] / 2;           // 800000
    const int EH = in_sizes[1];               // E*16 floats

    const int* src = ei;
    const int* dst = ei + E;

    float* out_nh = (float*)d_out;
    float* out_eh = (float*)d_out + (size_t)N * D_OUT;

    // Workspace:
    //   region A [0 .. N*D_HID*4): h1 during MLP, then edge bucketing buffers
    //   region B: n_h [N*D_OUT floats]
    char* ws = (char*)d_ws;
    float* h1  = (float*)ws;
    float* n_h = (float*)(ws + (size_t)N * D_HID * 4);

    unsigned int* sorted = (unsigned int*)ws;                          // E
    unsigned int* count  = (unsigned int*)(ws + (size_t)E * 4);        // N
    unsigned int* cursor = (unsigned int*)(ws + (size_t)E * 4 + (size_t)N * 4); // N
    unsigned int* off    = (unsigned int*)(ws + (size_t)E * 4 + (size_t)N * 8); // N+1

    // 1) h1 = relu(nh @ W1 + b1)
    {
        dim3 grid(D_HID / 64, (N + 63) / 64);
        gemm_bias_act<<<grid, 256, 0, stream>>>(nh, W1, b1, h1, N, D_HID, D_IN, 1);
    }
    // 2) n_h = h1 @ W2 + b2
    {
        dim3 grid(D_OUT / 64, (N + 63) / 64);
        gemm_bias_act<<<grid, 256, 0, stream>>>(h1, W2, b2, n_h, N, D_OUT, D_HID, 0);
    }
    // 3) bucket edges by dst (region A is free now)
    zero2<<<(N + 255) / 256, 256, 0, stream>>>(count, cursor, N);
    hist_dst<<<(E + 255) / 256, 256, 0, stream>>>(dst, count, E);
    scan_block<<<1, 1024, 0, stream>>>(count, off, N);
    fill_sorted<<<(E + 255) / 256, 256, 0, stream>>>(dst, off, cursor, sorted, E);

    // 4) fused online-softmax aggregation, one wave per node
    {
        int waves_per_block = 4;  // 256 threads
        int blocks = (N + waves_per_block - 1) / waves_per_block;
        node_aggregate<<<blocks, 256, 0, stream>>>(n_h, off, sorted, src, out_nh, N);
    }
    // 5) eh passthrough
    copy_f4<<<2048, 256, 0, stream>>>((const float4*)eh, (float4*)out_eh, EH / 4);
}

// Round 4
// 336.454 us; speedup vs baseline: 3.0470x; 1.3871x over previous
//
#include <hip/hip_runtime.h>
#include <math.h>

// ---------------------------------------------------------------------------
// GAT layer. Split-bf16 (hi/lo) MFMA MLP for fp32-level accuracy + bucketed
// online-softmax aggregation with bf16 gathers.
//   n_h = relu(nh@W1+b1)@W2+b2
//   attn[e] = dot(n_h[src], n_h[dst]);  segment-softmax over dst
//   out0 = n_h + segsum(softmax * n_h[src]);  out1 = eh
// ---------------------------------------------------------------------------

#define D_IN   128
#define D_HID  256
#define D_OUT  128

typedef short bf16x8 __attribute__((ext_vector_type(8)));
typedef float f32x4  __attribute__((ext_vector_type(4)));

__device__ __forceinline__ short f2bf(float f)
{
    unsigned int u = __float_as_uint(f);
    unsigned int r = (u + 0x7fffu + ((u >> 16) & 1u)) >> 16;   // RNE
    return (short)r;
}
__device__ __forceinline__ float bf2f(short h)
{
    return __uint_as_float(((unsigned int)(unsigned short)h) << 16);
}

// ---------------------------------------------------------------------------
// pack W[K][N] fp32 into MFMA B-fragment hi/lo bf16 planes:
//   plane[((c*T + t)*64 + l)*8 + j] = W[t*32 + (l>>4)*8 + j][c*16 + (l&15)]
// ---------------------------------------------------------------------------
__global__ __launch_bounds__(256)
void pack_w_split(const float* __restrict__ W, short* __restrict__ Bh,
                  short* __restrict__ Bl, int K, int N)
{
    int u = blockIdx.x * blockDim.x + threadIdx.x;
    const int T = K >> 5;
    const int total = (N >> 4) * T * 64;
    if (u >= total) return;
    const int l = u & 63;
    const int t = (u >> 6) % T;
    const int c = u / (64 * T);
    const int lr = l & 15, kb = l >> 4;
    bf16x8 vh, vl;
#pragma unroll
    for (int j = 0; j < 8; ++j) {
        int k   = t * 32 + kb * 8 + j;
        int col = c * 16 + lr;
        float x = W[(size_t)k * N + col];
        short hi = f2bf(x);
        vh[j] = hi;
        vl[j] = f2bf(x - bf2f(hi));
    }
    *(bf16x8*)(Bh + (size_t)u * 8) = vh;
    *(bf16x8*)(Bl + (size_t)u * 8) = vl;
}

// ---------------------------------------------------------------------------
// GEMM1: h1 = relu(A[N,128] @ W1 + b1) -> fp32 [Mp,256]
// A fp32, split in-register. 4 waves, BM=64; wave w -> cols [w*64, w*64+64)
// ---------------------------------------------------------------------------
__global__ __launch_bounds__(256)
void gemm1_mfma(const float* __restrict__ A, const short* __restrict__ Bh,
                const short* __restrict__ Bl, const float* __restrict__ bias,
                float* __restrict__ C, int Nvalid)
{
    const int w  = threadIdx.x >> 6;
    const int l  = threadIdx.x & 63;
    const int lr = l & 15, kb = l >> 4;
    const size_t row0 = (size_t)blockIdx.x * 64;

    f32x4 acc[4][4] = {};

#pragma unroll
    for (int t = 0; t < 4; ++t) {
        bf16x8 ah[4], al[4], bh[4], bl[4];
#pragma unroll
        for (int m = 0; m < 4; ++m) {
            size_t row = row0 + m * 16 + lr;
            float4 f0 = make_float4(0.f, 0.f, 0.f, 0.f), f1 = f0;
            if ((int)row < Nvalid) {
                const float* p = A + row * 128 + t * 32 + kb * 8;
                f0 = *(const float4*)p;
                f1 = *(const float4*)(p + 4);
            }
            float fv[8] = {f0.x, f0.y, f0.z, f0.w, f1.x, f1.y, f1.z, f1.w};
#pragma unroll
            for (int j = 0; j < 8; ++j) {
                short hi = f2bf(fv[j]);
                ah[m][j] = hi;
                al[m][j] = f2bf(fv[j] - bf2f(hi));
            }
        }
#pragma unroll
        for (int n = 0; n < 4; ++n) {
            int c = w * 4 + n;
            size_t boff = (size_t)((c * 4 + t) * 64 + l) * 8;
            bh[n] = *(const bf16x8*)(Bh + boff);
            bl[n] = *(const bf16x8*)(Bl + boff);
        }
#pragma unroll
        for (int m = 0; m < 4; ++m)
#pragma unroll
            for (int n = 0; n < 4; ++n) {
                acc[m][n] = __builtin_amdgcn_mfma_f32_16x16x32_bf16(ah[m], bh[n], acc[m][n], 0, 0, 0);
                acc[m][n] = __builtin_amdgcn_mfma_f32_16x16x32_bf16(al[m], bh[n], acc[m][n], 0, 0, 0);
                acc[m][n] = __builtin_amdgcn_mfma_f32_16x16x32_bf16(ah[m], bl[n], acc[m][n], 0, 0, 0);
            }
    }

#pragma unroll
    for (int n = 0; n < 4; ++n) {
        int col = w * 64 + n * 16 + lr;
        float bb = bias[col];
#pragma unroll
        for (int m = 0; m < 4; ++m)
#pragma unroll
            for (int i = 0; i < 4; ++i) {
                size_t row = row0 + m * 16 + kb * 4 + i;
                C[row * 256 + col] = fmaxf(acc[m][n][i] + bb, 0.f);
            }
    }
}

// ---------------------------------------------------------------------------
// GEMM2: n_h = h1[Mp,256] @ W2 + b2
//   -> fp32 rows [0,Nvalid) into out (d_out, self term)
//   -> bf16 all rows into nhb (gather plane)
// 4 waves, BM=128; wave (wr=w>>1, wc=w&1)
// ---------------------------------------------------------------------------
__global__ __launch_bounds__(256)
void gemm2_mfma(const float* __restrict__ A, const short* __restrict__ Bh,
                const short* __restrict__ Bl, const float* __restrict__ bias,
                float* __restrict__ out, short* __restrict__ nhb, int Nvalid)
{
    const int w  = threadIdx.x >> 6;
    const int l  = threadIdx.x & 63;
    const int lr = l & 15, kb = l >> 4;
    const int wr = w >> 1, wc = w & 1;
    const size_t row0 = (size_t)blockIdx.x * 128 + wr * 64;

    f32x4 acc[4][4] = {};
    const float* Ab = A + row0 * 256;

#pragma unroll
    for (int t = 0; t < 8; ++t) {
        bf16x8 ah[4], al[4], bh[4], bl[4];
#pragma unroll
        for (int m = 0; m < 4; ++m) {
            const float* p = Ab + (size_t)(m * 16 + lr) * 256 + t * 32 + kb * 8;
            float4 f0 = *(const float4*)p;
            float4 f1 = *(const float4*)(p + 4);
            float fv[8] = {f0.x, f0.y, f0.z, f0.w, f1.x, f1.y, f1.z, f1.w};
#pragma unroll
            for (int j = 0; j < 8; ++j) {
                short hi = f2bf(fv[j]);
                ah[m][j] = hi;
                al[m][j] = f2bf(fv[j] - bf2f(hi));
            }
        }
#pragma unroll
        for (int n = 0; n < 4; ++n) {
            int c = wc * 4 + n;
            size_t boff = (size_t)((c * 8 + t) * 64 + l) * 8;
            bh[n] = *(const bf16x8*)(Bh + boff);
            bl[n] = *(const bf16x8*)(Bl + boff);
        }
#pragma unroll
        for (int m = 0; m < 4; ++m)
#pragma unroll
            for (int n = 0; n < 4; ++n) {
                acc[m][n] = __builtin_amdgcn_mfma_f32_16x16x32_bf16(ah[m], bh[n], acc[m][n], 0, 0, 0);
                acc[m][n] = __builtin_amdgcn_mfma_f32_16x16x32_bf16(al[m], bh[n], acc[m][n], 0, 0, 0);
                acc[m][n] = __builtin_amdgcn_mfma_f32_16x16x32_bf16(ah[m], bl[n], acc[m][n], 0, 0, 0);
            }
    }

#pragma unroll
    for (int n = 0; n < 4; ++n) {
        int col = wc * 64 + n * 16 + lr;
        float bb = bias[col];
#pragma unroll
        for (int m = 0; m < 4; ++m)
#pragma unroll
            for (int i = 0; i < 4; ++i) {
                size_t row = row0 + m * 16 + kb * 4 + i;
                float v = acc[m][n][i] + bb;
                nhb[row * 128 + col] = f2bf(v);
                if ((int)row < Nvalid) out[row * 128 + col] = v;
            }
    }
}

// ---------------------------------------------------------------------------
// bucketing: histogram, scan, fill (stores src VALUES)
// ---------------------------------------------------------------------------
__global__ void zero2(unsigned int* __restrict__ a, unsigned int* __restrict__ b,
                      int n)
{
    int i = blockIdx.x * blockDim.x + threadIdx.x;
    if (i < n) { a[i] = 0u; b[i] = 0u; }
}

__global__ __launch_bounds__(256)
void hist_dst(const int* __restrict__ dst, unsigned int* __restrict__ count, int E)
{
    int e = blockIdx.x * blockDim.x + threadIdx.x;
    if (e < E) atomicAdd(count + dst[e], 1u);
}

__global__ __launch_bounds__(1024)
void scan_block(const unsigned int* __restrict__ count,
                unsigned int* __restrict__ off, int n)
{
    __shared__ unsigned int lds[1024];
    const int tid = threadIdx.x;
    const int CH = (n + 1023) / 1024;
    const int lo = tid * CH;
    const int hi = min(lo + CH, n);

    unsigned int s = 0;
    for (int j = lo; j < hi; ++j) s += count[j];
    lds[tid] = s;
    __syncthreads();
    for (int d = 1; d < 1024; d <<= 1) {
        unsigned int v = lds[tid];
        unsigned int add = (tid >= d) ? lds[tid - d] : 0u;
        __syncthreads();
        lds[tid] = v + add;
        __syncthreads();
    }
    unsigned int run = lds[tid] - s;
    for (int j = lo; j < hi; ++j) { off[j] = run; run += count[j]; }
    if (tid == 1023) off[n] = lds[1023];
}

__global__ __launch_bounds__(256)
void fill_srcs(const int* __restrict__ src, const int* __restrict__ dst,
               const unsigned int* __restrict__ off,
               unsigned int* __restrict__ cursor, int* __restrict__ srcs, int E)
{
    int e = blockIdx.x * blockDim.x + threadIdx.x;
    if (e >= E) return;
    int d = dst[e];
    unsigned int pos = atomicAdd(cursor + d, 1u);
    srcs[off[d] + pos] = src[e];
}

// ---------------------------------------------------------------------------
// One wave per dst node: online softmax over incident edges.
// self (and dot dst-side) fp32 from out; src gathers bf16. In-place update.
// ---------------------------------------------------------------------------
__global__ __launch_bounds__(256)
void node_aggregate(const short* __restrict__ nhb,
                    const unsigned int* __restrict__ off,
                    const int* __restrict__ srcs,
                    float* __restrict__ out, int N)
{
    int wid  = (blockIdx.x * blockDim.x + threadIdx.x) >> 6;
    int lane = threadIdx.x & 63;
    if (wid >= N) return;

    const unsigned int beg = off[wid];
    const unsigned int end = off[wid + 1];

    float2 self = *(const float2*)(out + (size_t)wid * D_OUT + lane * 2);

    float m = -INFINITY;
    float denom = 0.f;
    float accx = 0.f, accy = 0.f;

    for (unsigned int i = beg; i < end; ++i) {
        int s = srcs[i];                     // wave-uniform
        unsigned int au = *(const unsigned int*)(nhb + (size_t)s * D_OUT + lane * 2);
        float ax = __uint_as_float(au << 16);
        float ay = __uint_as_float(au & 0xffff0000u);
        float p = ax * self.x + ay * self.y;
#pragma unroll
        for (int o = 32; o > 0; o >>= 1) p += __shfl_xor(p, o);
        float mnew  = fmaxf(m, p);
        float scale = __expf(m - mnew);      // 0 on first iter
        float wgt   = __expf(p - mnew);
        denom = denom * scale + wgt;
        accx  = accx * scale + wgt * ax;
        accy  = accy * scale + wgt * ay;
        m = mnew;
    }

    float inv = (denom > 0.f) ? 1.f / denom : 0.f;
    float2 o;
    o.x = self.x + accx * inv;
    o.y = self.y + accy * inv;
    *(float2*)(out + (size_t)wid * D_OUT + lane * 2) = o;
}

// ---------------------------------------------------------------------------
__global__ __launch_bounds__(256)
void copy_f4(const float4* __restrict__ in, float4* __restrict__ out, int n4)
{
    int i = blockIdx.x * blockDim.x + threadIdx.x;
    int stride = gridDim.x * blockDim.x;
    for (; i < n4; i += stride) out[i] = in[i];
}

// ---------------------------------------------------------------------------
extern "C" void kernel_launch(void* const* d_in, const int* in_sizes, int n_in,
                              void* d_out, int out_size, void* d_ws, size_t ws_size,
                              hipStream_t stream)
{
    const float* nh  = (const float*)d_in[0];
    const float* eh  = (const float*)d_in[1];
    const int*   ei  = (const int*)d_in[2];
    const float* W1  = (const float*)d_in[3];
    const float* b1  = (const float*)d_in[4];
    const float* W2  = (const float*)d_in[5];
    const float* b2  = (const float*)d_in[6];

    const int N  = in_sizes[0] / D_IN;        // 50000
    const int E  = in_sizes[2] / 2;           // 800000
    const int EH = in_sizes[1];               // E*16 floats
    const int Mp = (N + 127) & ~127;          // padded rows (50048)

    const int* src = ei;
    const int* dst = ei + E;

    float* out_nh = (float*)d_out;
    float* out_eh = (float*)d_out + (size_t)N * D_OUT;

    // workspace layout (~68 MB)
    char* ws = (char*)d_ws;
    size_t o = 0;
    float* h1  = (float*)(ws + o); o += (size_t)Mp * D_HID * 4;   // 51.2 MB
    short* nhb = (short*)(ws + o); o += (size_t)Mp * D_OUT * 2;   // 12.8 MB
    short* B1h = (short*)(ws + o); o += (size_t)D_IN  * D_HID * 2;
    short* B1l = (short*)(ws + o); o += (size_t)D_IN  * D_HID * 2;
    short* B2h = (short*)(ws + o); o += (size_t)D_HID * D_OUT * 2;
    short* B2l = (short*)(ws + o); o += (size_t)D_HID * D_OUT * 2;
    int*          srcs   = (int*)(ws + o);          o += (size_t)E * 4;
    unsigned int* count  = (unsigned int*)(ws + o); o += (size_t)N * 4;
    unsigned int* cursor = (unsigned int*)(ws + o); o += (size_t)N * 4;
    unsigned int* off    = (unsigned int*)(ws + o); o += (size_t)(N + 1) * 4;

    // 1) weight packs (hi/lo)
    pack_w_split<<<16, 256, 0, stream>>>(W1, B1h, B1l, D_IN, D_HID);
    pack_w_split<<<16, 256, 0, stream>>>(W2, B2h, B2l, D_HID, D_OUT);

    // 2) bucket edges by dst
    zero2<<<(N + 255) / 256, 256, 0, stream>>>(count, cursor, N);
    hist_dst<<<(E + 255) / 256, 256, 0, stream>>>(dst, count, E);
    scan_block<<<1, 1024, 0, stream>>>(count, off, N);
    fill_srcs<<<(E + 255) / 256, 256, 0, stream>>>(src, dst, off, cursor, srcs, E);

    // 3) MLP (split-bf16 MFMA, fp32 staging)
    gemm1_mfma<<<Mp / 64, 256, 0, stream>>>(nh, B1h, B1l, b1, h1, N);
    gemm2_mfma<<<Mp / 128, 256, 0, stream>>>(h1, B2h, B2l, b2, out_nh, nhb, N);

    // 4) fused online-softmax aggregation, one wave per node
    node_aggregate<<<(N + 3) / 4, 256, 0, stream>>>(nhb, off, srcs, out_nh, N);

    // 5) eh passthrough
    copy_f4<<<2048, 256, 0, stream>>>((const float4*)eh, (float4*)out_eh, EH / 4);
}

// Round 5
// 298.478 us; speedup vs baseline: 3.4347x; 1.1272x over previous
//
#include <hip/hip_runtime.h>
#include <math.h>

// ---------------------------------------------------------------------------
// GAT layer. Fused split-bf16 MFMA MLP (h1 staged in LDS, never touches HBM)
// + bucketed online-softmax aggregation with 4x-unrolled edge loop.
//   n_h = relu(nh@W1+b1)@W2+b2
//   attn[e] = dot(n_h[src], n_h[dst]);  segment-softmax over dst
//   out0 = n_h + segsum(softmax * n_h[src]);  out1 = eh
// ---------------------------------------------------------------------------

#define D_IN   128
#define D_HID  256
#define D_OUT  128

typedef short bf16x8 __attribute__((ext_vector_type(8)));
typedef float f32x4  __attribute__((ext_vector_type(4)));

__device__ __forceinline__ short f2bf(float f)
{
    unsigned int u = __float_as_uint(f);
    unsigned int r = (u + 0x7fffu + ((u >> 16) & 1u)) >> 16;   // RNE
    return (short)r;
}
__device__ __forceinline__ float bf2f(short h)
{
    return __uint_as_float(((unsigned int)(unsigned short)h) << 16);
}

// ---------------------------------------------------------------------------
// pack W[K][N] fp32 into MFMA B-fragment hi/lo bf16 planes:
//   plane[((c*T + t)*64 + l)*8 + j] = W[t*32 + (l>>4)*8 + j][c*16 + (l&15)]
// ---------------------------------------------------------------------------
__global__ __launch_bounds__(256)
void pack_w_split(const float* __restrict__ W, short* __restrict__ Bh,
                  short* __restrict__ Bl, int K, int N)
{
    int u = blockIdx.x * blockDim.x + threadIdx.x;
    const int T = K >> 5;
    const int total = (N >> 4) * T * 64;
    if (u >= total) return;
    const int l = u & 63;
    const int t = (u >> 6) % T;
    const int c = u / (64 * T);
    const int lr = l & 15, kb = l >> 4;
    bf16x8 vh, vl;
#pragma unroll
    for (int j = 0; j < 8; ++j) {
        int k   = t * 32 + kb * 8 + j;
        int col = c * 16 + lr;
        float x = W[(size_t)k * N + col];
        short hi = f2bf(x);
        vh[j] = hi;
        vl[j] = f2bf(x - bf2f(hi));
    }
    *(bf16x8*)(Bh + (size_t)u * 8) = vh;
    *(bf16x8*)(Bl + (size_t)u * 8) = vl;
}

// ---------------------------------------------------------------------------
// Fused MLP: out/nhb = relu(A@W1+b1)@W2+b2, h1 staged in LDS (hi/lo bf16),
// processed in two 128-col halves to keep LDS at 34 KB (4 blocks/CU).
// Block: 256 thr (4 waves), 64 rows. Per half h:
//   gemm1: wave w computes h1 cols [h*128 + w*32, +32)  (acc1[4][2])
//   gemm2: wave w accumulates out cols [w*32, +32) over k in this half
// ---------------------------------------------------------------------------
#define H_STRIDE 136   // 128 + 8 bf16 pad

__global__ __launch_bounds__(256)
void mlp_fused(const float* __restrict__ A,
               const short* __restrict__ B1h, const short* __restrict__ B1l,
               const float* __restrict__ b1,
               const short* __restrict__ B2h, const short* __restrict__ B2l,
               const float* __restrict__ b2,
               float* __restrict__ out, short* __restrict__ nhb, int Nvalid)
{
    __shared__ __attribute__((aligned(16))) short Hh[64 * H_STRIDE];
    __shared__ __attribute__((aligned(16))) short Hl[64 * H_STRIDE];

    const int w  = threadIdx.x >> 6;
    const int l  = threadIdx.x & 63;
    const int lr = l & 15, kb = l >> 4;
    const size_t row0 = (size_t)blockIdx.x * 64;

    f32x4 acc2[4][2] = {};

#pragma unroll
    for (int h = 0; h < 2; ++h) {
        // ---- GEMM1 for this col-half: acc1 = A[64,128] @ W1[:, h*128+w*32 ..]
        f32x4 acc1[4][2] = {};
#pragma unroll
        for (int t = 0; t < 4; ++t) {
            bf16x8 ah[4], al[4], bh[2], bl[2];
#pragma unroll
            for (int m = 0; m < 4; ++m) {
                size_t row = row0 + m * 16 + lr;
                float4 f0 = make_float4(0.f, 0.f, 0.f, 0.f), f1 = f0;
                if ((int)row < Nvalid) {
                    const float* p = A + row * D_IN + t * 32 + kb * 8;
                    f0 = *(const float4*)p;
                    f1 = *(const float4*)(p + 4);
                }
                float fv[8] = {f0.x, f0.y, f0.z, f0.w, f1.x, f1.y, f1.z, f1.w};
#pragma unroll
                for (int j = 0; j < 8; ++j) {
                    short hi = f2bf(fv[j]);
                    ah[m][j] = hi;
                    al[m][j] = f2bf(fv[j] - bf2f(hi));
                }
            }
#pragma unroll
            for (int n = 0; n < 2; ++n) {
                int c = h * 8 + w * 2 + n;           // h1 col-frag index
                size_t boff = (size_t)((c * 4 + t) * 64 + l) * 8;
                bh[n] = *(const bf16x8*)(B1h + boff);
                bl[n] = *(const bf16x8*)(B1l + boff);
            }
#pragma unroll
            for (int m = 0; m < 4; ++m)
#pragma unroll
                for (int n = 0; n < 2; ++n) {
                    acc1[m][n] = __builtin_amdgcn_mfma_f32_16x16x32_bf16(ah[m], bh[n], acc1[m][n], 0, 0, 0);
                    acc1[m][n] = __builtin_amdgcn_mfma_f32_16x16x32_bf16(al[m], bh[n], acc1[m][n], 0, 0, 0);
                    acc1[m][n] = __builtin_amdgcn_mfma_f32_16x16x32_bf16(ah[m], bl[n], acc1[m][n], 0, 0, 0);
                }
        }
        // ---- bias + relu + split -> LDS
        if (h) __syncthreads();                      // protect previous half's reads
#pragma unroll
        for (int n = 0; n < 2; ++n) {
            int lcol = w * 32 + n * 16 + lr;         // 0..127 within half
            float bb = b1[h * 128 + lcol];
#pragma unroll
            for (int m = 0; m < 4; ++m)
#pragma unroll
                for (int i = 0; i < 4; ++i) {
                    int lrow = m * 16 + kb * 4 + i;
                    float v = fmaxf(acc1[m][n][i] + bb, 0.f);
                    short hi = f2bf(v);
                    Hh[lrow * H_STRIDE + lcol] = hi;
                    Hl[lrow * H_STRIDE + lcol] = f2bf(v - bf2f(hi));
                }
        }
        __syncthreads();

        // ---- GEMM2 partial: acc2 += h1_half[64,128] @ W2[h*128.., w*32..]
#pragma unroll
        for (int t2 = 0; t2 < 4; ++t2) {
            bf16x8 ah[4], al[4], bh[2], bl[2];
#pragma unroll
            for (int m = 0; m < 4; ++m) {
                const short* p = &Hh[(m * 16 + lr) * H_STRIDE + t2 * 32 + kb * 8];
                ah[m] = *(const bf16x8*)p;
                al[m] = *(const bf16x8*)(p + 64 * H_STRIDE);   // Hl follows Hh? no:
            }
            // (Hl is a separate array; fix the lo loads below)
#pragma unroll
            for (int m = 0; m < 4; ++m)
                al[m] = *(const bf16x8*)&Hl[(m * 16 + lr) * H_STRIDE + t2 * 32 + kb * 8];
#pragma unroll
            for (int n = 0; n < 2; ++n) {
                int c = w * 2 + n;                   // out col-frag index
                size_t boff = (size_t)((c * 8 + (h * 4 + t2)) * 64 + l) * 8;
                bh[n] = *(const bf16x8*)(B2h + boff);
                bl[n] = *(const bf16x8*)(B2l + boff);
            }
#pragma unroll
            for (int m = 0; m < 4; ++m)
#pragma unroll
                for (int n = 0; n < 2; ++n) {
                    acc2[m][n] = __builtin_amdgcn_mfma_f32_16x16x32_bf16(ah[m], bh[n], acc2[m][n], 0, 0, 0);
                    acc2[m][n] = __builtin_amdgcn_mfma_f32_16x16x32_bf16(al[m], bh[n], acc2[m][n], 0, 0, 0);
                    acc2[m][n] = __builtin_amdgcn_mfma_f32_16x16x32_bf16(ah[m], bl[n], acc2[m][n], 0, 0, 0);
                }
        }
    }

    // ---- epilogue: bias, write fp32 self-term + bf16 gather plane
#pragma unroll
    for (int n = 0; n < 2; ++n) {
        int col = w * 32 + n * 16 + lr;
        float bb = b2[col];
#pragma unroll
        for (int m = 0; m < 4; ++m)
#pragma unroll
            for (int i = 0; i < 4; ++i) {
                size_t row = row0 + m * 16 + kb * 4 + i;
                float v = acc2[m][n][i] + bb;
                nhb[row * D_OUT + col] = f2bf(v);
                if ((int)row < Nvalid) out[row * D_OUT + col] = v;
            }
    }
}

// ---------------------------------------------------------------------------
// bucketing: histogram, scan, fill (stores src VALUES)
// ---------------------------------------------------------------------------
__global__ void zero2(unsigned int* __restrict__ a, unsigned int* __restrict__ b,
                      int n)
{
    int i = blockIdx.x * blockDim.x + threadIdx.x;
    if (i < n) { a[i] = 0u; b[i] = 0u; }
}

__global__ __launch_bounds__(256)
void hist_dst(const int* __restrict__ dst, unsigned int* __restrict__ count, int E)
{
    int e = blockIdx.x * blockDim.x + threadIdx.x;
    if (e < E) atomicAdd(count + dst[e], 1u);
}

__global__ __launch_bounds__(1024)
void scan_block(const unsigned int* __restrict__ count,
                unsigned int* __restrict__ off, int n)
{
    __shared__ unsigned int lds[1024];
    const int tid = threadIdx.x;
    const int CH = (n + 1023) / 1024;
    const int lo = tid * CH;
    const int hi = min(lo + CH, n);

    unsigned int s = 0;
    for (int j = lo; j < hi; ++j) s += count[j];
    lds[tid] = s;
    __syncthreads();
    for (int d = 1; d < 1024; d <<= 1) {
        unsigned int v = lds[tid];
        unsigned int add = (tid >= d) ? lds[tid - d] : 0u;
        __syncthreads();
        lds[tid] = v + add;
        __syncthreads();
    }
    unsigned int run = lds[tid] - s;
    for (int j = lo; j < hi; ++j) { off[j] = run; run += count[j]; }
    if (tid == 1023) off[n] = lds[1023];
}

__global__ __launch_bounds__(256)
void fill_srcs(const int* __restrict__ src, const int* __restrict__ dst,
               const unsigned int* __restrict__ off,
               unsigned int* __restrict__ cursor, int* __restrict__ srcs, int E)
{
    int e = blockIdx.x * blockDim.x + threadIdx.x;
    if (e >= E) return;
    int d = dst[e];
    unsigned int pos = atomicAdd(cursor + d, 1u);
    srcs[off[d] + pos] = src[e];
}

// ---------------------------------------------------------------------------
// One wave per dst node, 4x-unrolled online softmax over incident edges.
// self fp32 from out; src gathers bf16. In-place update of out.
// ---------------------------------------------------------------------------
__device__ __forceinline__ float hi16f(unsigned int u) { return __uint_as_float(u << 16); }
__device__ __forceinline__ float lo16f(unsigned int u) { return __uint_as_float(u & 0xffff0000u); }

__global__ __launch_bounds__(256)
void node_aggregate(const short* __restrict__ nhb,
                    const unsigned int* __restrict__ off,
                    const int* __restrict__ srcs,
                    float* __restrict__ out, int N)
{
    int wid  = (blockIdx.x * blockDim.x + threadIdx.x) >> 6;
    int lane = threadIdx.x & 63;
    if (wid >= N) return;

    const unsigned int beg = off[wid];
    const unsigned int end = off[wid + 1];

    float2 self = *(const float2*)(out + (size_t)wid * D_OUT + lane * 2);

    float m = -INFINITY;
    float denom = 0.f, accx = 0.f, accy = 0.f;

    unsigned int i = beg;
    for (; i + 4 <= end; i += 4) {
        int s0 = srcs[i + 0], s1 = srcs[i + 1], s2 = srcs[i + 2], s3 = srcs[i + 3];
        unsigned int a0 = *(const unsigned int*)(nhb + (size_t)s0 * D_OUT + lane * 2);
        unsigned int a1 = *(const unsigned int*)(nhb + (size_t)s1 * D_OUT + lane * 2);
        unsigned int a2 = *(const unsigned int*)(nhb + (size_t)s2 * D_OUT + lane * 2);
        unsigned int a3 = *(const unsigned int*)(nhb + (size_t)s3 * D_OUT + lane * 2);
        float ax0 = hi16f(a0), ay0 = lo16f(a0);
        float ax1 = hi16f(a1), ay1 = lo16f(a1);
        float ax2 = hi16f(a2), ay2 = lo16f(a2);
        float ax3 = hi16f(a3), ay3 = lo16f(a3);
        float p0 = ax0 * self.x + ay0 * self.y;
        float p1 = ax1 * self.x + ay1 * self.y;
        float p2 = ax2 * self.x + ay2 * self.y;
        float p3 = ax3 * self.x + ay3 * self.y;
#pragma unroll
        for (int o = 32; o > 0; o >>= 1) {
            p0 += __shfl_xor(p0, o);
            p1 += __shfl_xor(p1, o);
            p2 += __shfl_xor(p2, o);
            p3 += __shfl_xor(p3, o);
        }
        float pm   = fmaxf(fmaxf(p0, p1), fmaxf(p2, p3));
        float mnew = fmaxf(m, pm);
        float scale = __expf(m - mnew);          // 0 on first iter
        float w0 = __expf(p0 - mnew), w1 = __expf(p1 - mnew);
        float w2 = __expf(p2 - mnew), w3 = __expf(p3 - mnew);
        denom = denom * scale + ((w0 + w1) + (w2 + w3));
        accx  = accx  * scale + ((w0 * ax0 + w1 * ax1) + (w2 * ax2 + w3 * ax3));
        accy  = accy  * scale + ((w0 * ay0 + w1 * ay1) + (w2 * ay2 + w3 * ay3));
        m = mnew;
    }
    for (; i < end; ++i) {
        int s = srcs[i];
        unsigned int au = *(const unsigned int*)(nhb + (size_t)s * D_OUT + lane * 2);
        float ax = hi16f(au), ay = lo16f(au);
        float p = ax * self.x + ay * self.y;
#pragma unroll
        for (int o = 32; o > 0; o >>= 1) p += __shfl_xor(p, o);
        float mnew  = fmaxf(m, p);
        float scale = __expf(m - mnew);
        float wgt   = __expf(p - mnew);
        denom = denom * scale + wgt;
        accx  = accx * scale + wgt * ax;
        accy  = accy * scale + wgt * ay;
        m = mnew;
    }

    float inv = (denom > 0.f) ? 1.f / denom : 0.f;
    float2 o;
    o.x = self.x + accx * inv;
    o.y = self.y + accy * inv;
    *(float2*)(out + (size_t)wid * D_OUT + lane * 2) = o;
}

// ---------------------------------------------------------------------------
__global__ __launch_bounds__(256)
void copy_f4(const float4* __restrict__ in, float4* __restrict__ out, int n4)
{
    int i = blockIdx.x * blockDim.x + threadIdx.x;
    int stride = gridDim.x * blockDim.x;
    for (; i < n4; i += stride) out[i] = in[i];
}

// ---------------------------------------------------------------------------
extern "C" void kernel_launch(void* const* d_in, const int* in_sizes, int n_in,
                              void* d_out, int out_size, void* d_ws, size_t ws_size,
                              hipStream_t stream)
{
    const float* nh  = (const float*)d_in[0];
    const float* eh  = (const float*)d_in[1];
    const int*   ei  = (const int*)d_in[2];
    const float* W1  = (const float*)d_in[3];
    const float* b1  = (const float*)d_in[4];
    const float* W2  = (const float*)d_in[5];
    const float* b2  = (const float*)d_in[6];

    const int N  = in_sizes[0] / D_IN;        // 50000
    const int E  = in_sizes[2] / 2;           // 800000
    const int EH = in_sizes[1];               // E*16 floats
    const int Mp = (N + 63) & ~63;            // padded rows (50048)

    const int* src = ei;
    const int* dst = ei + E;

    float* out_nh = (float*)d_out;
    float* out_eh = (float*)d_out + (size_t)N * D_OUT;

    // workspace (~17 MB)
    char* ws = (char*)d_ws;
    size_t o = 0;
    short* nhb = (short*)(ws + o); o += (size_t)Mp * D_OUT * 2;
    short* B1h = (short*)(ws + o); o += (size_t)D_IN  * D_HID * 2;
    short* B1l = (short*)(ws + o); o += (size_t)D_IN  * D_HID * 2;
    short* B2h = (short*)(ws + o); o += (size_t)D_HID * D_OUT * 2;
    short* B2l = (short*)(ws + o); o += (size_t)D_HID * D_OUT * 2;
    int*          srcs   = (int*)(ws + o);          o += (size_t)E * 4;
    unsigned int* count  = (unsigned int*)(ws + o); o += (size_t)N * 4;
    unsigned int* cursor = (unsigned int*)(ws + o); o += (size_t)N * 4;
    unsigned int* off    = (unsigned int*)(ws + o); o += (size_t)(N + 1) * 4;

    // 1) weight packs (hi/lo)
    pack_w_split<<<16, 256, 0, stream>>>(W1, B1h, B1l, D_IN, D_HID);
    pack_w_split<<<16, 256, 0, stream>>>(W2, B2h, B2l, D_HID, D_OUT);

    // 2) bucket edges by dst
    zero2<<<(N + 255) / 256, 256, 0, stream>>>(count, cursor, N);
    hist_dst<<<(E + 255) / 256, 256, 0, stream>>>(dst, count, E);
    scan_block<<<1, 1024, 0, stream>>>(count, off, N);
    fill_srcs<<<(E + 255) / 256, 256, 0, stream>>>(src, dst, off, cursor, srcs, E);

    // 3) fused MLP (split-bf16 MFMA, h1 in LDS)
    mlp_fused<<<Mp / 64, 256, 0, stream>>>(nh, B1h, B1l, b1, B2h, B2l, b2,
                                           out_nh, nhb, N);

    // 4) fused online-softmax aggregation, one wave per node
    node_aggregate<<<(N + 3) / 4, 256, 0, stream>>>(nhb, off, srcs, out_nh, N);

    // 5) eh passthrough
    copy_f4<<<2048, 256, 0, stream>>>((const float4*)eh, (float4*)out_eh, EH / 4);
}

// Round 6
// 201.220 us; speedup vs baseline: 5.0948x; 1.4833x over previous
//
#include <hip/hip_runtime.h>
#include <math.h>

// ---------------------------------------------------------------------------
// GAT layer. Fused split-bf16 MFMA MLP (h1 staged in LDS) + bucketed
// online-softmax aggregation (4x-unrolled). Hierarchical coalesced scan.
//   n_h = relu(nh@W1+b1)@W2+b2
//   attn[e] = dot(n_h[src], n_h[dst]);  segment-softmax over dst
//   out0 = n_h + segsum(softmax * n_h[src]);  out1 = eh
// ---------------------------------------------------------------------------

#define D_IN   128
#define D_HID  256
#define D_OUT  128

typedef short bf16x8 __attribute__((ext_vector_type(8)));
typedef float f32x4  __attribute__((ext_vector_type(4)));

__device__ __forceinline__ short f2bf(float f)
{
    unsigned int u = __float_as_uint(f);
    unsigned int r = (u + 0x7fffu + ((u >> 16) & 1u)) >> 16;   // RNE
    return (short)r;
}
__device__ __forceinline__ float bf2f(short h)
{
    return __uint_as_float(((unsigned int)(unsigned short)h) << 16);
}

// ---------------------------------------------------------------------------
// pack W[K][N] fp32 into MFMA B-fragment hi/lo bf16 planes:
//   plane[((c*T + t)*64 + l)*8 + j] = W[t*32 + (l>>4)*8 + j][c*16 + (l&15)]
// ---------------------------------------------------------------------------
__global__ __launch_bounds__(256)
void pack_w_split(const float* __restrict__ W, short* __restrict__ Bh,
                  short* __restrict__ Bl, int K, int N)
{
    int u = blockIdx.x * blockDim.x + threadIdx.x;
    const int T = K >> 5;
    const int total = (N >> 4) * T * 64;
    if (u >= total) return;
    const int l = u & 63;
    const int t = (u >> 6) % T;
    const int c = u / (64 * T);
    const int lr = l & 15, kb = l >> 4;
    bf16x8 vh, vl;
#pragma unroll
    for (int j = 0; j < 8; ++j) {
        int k   = t * 32 + kb * 8 + j;
        int col = c * 16 + lr;
        float x = W[(size_t)k * N + col];
        short hi = f2bf(x);
        vh[j] = hi;
        vl[j] = f2bf(x - bf2f(hi));
    }
    *(bf16x8*)(Bh + (size_t)u * 8) = vh;
    *(bf16x8*)(Bl + (size_t)u * 8) = vl;
}

// ---------------------------------------------------------------------------
// Fused MLP: out/nhb = relu(A@W1+b1)@W2+b2, h1 staged in LDS (hi/lo bf16),
// two 128-col halves, 34 KB LDS. 256 thr (4 waves), 64 rows per block.
// ---------------------------------------------------------------------------
#define H_STRIDE 136   // 128 + 8 bf16 pad

__global__ __launch_bounds__(256)
void mlp_fused(const float* __restrict__ A,
               const short* __restrict__ B1h, const short* __restrict__ B1l,
               const float* __restrict__ b1,
               const short* __restrict__ B2h, const short* __restrict__ B2l,
               const float* __restrict__ b2,
               float* __restrict__ out, short* __restrict__ nhb, int Nvalid)
{
    __shared__ __attribute__((aligned(16))) short Hh[64 * H_STRIDE];
    __shared__ __attribute__((aligned(16))) short Hl[64 * H_STRIDE];

    const int w  = threadIdx.x >> 6;
    const int l  = threadIdx.x & 63;
    const int lr = l & 15, kb = l >> 4;
    const size_t row0 = (size_t)blockIdx.x * 64;

    f32x4 acc2[4][2] = {};

#pragma unroll
    for (int h = 0; h < 2; ++h) {
        // ---- GEMM1 for this col-half
        f32x4 acc1[4][2] = {};
#pragma unroll
        for (int t = 0; t < 4; ++t) {
            bf16x8 ah[4], al[4], bh[2], bl[2];
#pragma unroll
            for (int m = 0; m < 4; ++m) {
                size_t row = row0 + m * 16 + lr;
                float4 f0 = make_float4(0.f, 0.f, 0.f, 0.f), f1 = f0;
                if ((int)row < Nvalid) {
                    const float* p = A + row * D_IN + t * 32 + kb * 8;
                    f0 = *(const float4*)p;
                    f1 = *(const float4*)(p + 4);
                }
                float fv[8] = {f0.x, f0.y, f0.z, f0.w, f1.x, f1.y, f1.z, f1.w};
#pragma unroll
                for (int j = 0; j < 8; ++j) {
                    short hi = f2bf(fv[j]);
                    ah[m][j] = hi;
                    al[m][j] = f2bf(fv[j] - bf2f(hi));
                }
            }
#pragma unroll
            for (int n = 0; n < 2; ++n) {
                int c = h * 8 + w * 2 + n;
                size_t boff = (size_t)((c * 4 + t) * 64 + l) * 8;
                bh[n] = *(const bf16x8*)(B1h + boff);
                bl[n] = *(const bf16x8*)(B1l + boff);
            }
#pragma unroll
            for (int m = 0; m < 4; ++m)
#pragma unroll
                for (int n = 0; n < 2; ++n) {
                    acc1[m][n] = __builtin_amdgcn_mfma_f32_16x16x32_bf16(ah[m], bh[n], acc1[m][n], 0, 0, 0);
                    acc1[m][n] = __builtin_amdgcn_mfma_f32_16x16x32_bf16(al[m], bh[n], acc1[m][n], 0, 0, 0);
                    acc1[m][n] = __builtin_amdgcn_mfma_f32_16x16x32_bf16(ah[m], bl[n], acc1[m][n], 0, 0, 0);
                }
        }
        // ---- bias + relu + split -> LDS
        if (h) __syncthreads();
#pragma unroll
        for (int n = 0; n < 2; ++n) {
            int lcol = w * 32 + n * 16 + lr;
            float bb = b1[h * 128 + lcol];
#pragma unroll
            for (int m = 0; m < 4; ++m)
#pragma unroll
                for (int i = 0; i < 4; ++i) {
                    int lrow = m * 16 + kb * 4 + i;
                    float v = fmaxf(acc1[m][n][i] + bb, 0.f);
                    short hi = f2bf(v);
                    Hh[lrow * H_STRIDE + lcol] = hi;
                    Hl[lrow * H_STRIDE + lcol] = f2bf(v - bf2f(hi));
                }
        }
        __syncthreads();

        // ---- GEMM2 partial accumulate over this half's K
#pragma unroll
        for (int t2 = 0; t2 < 4; ++t2) {
            bf16x8 ah[4], al[4], bh[2], bl[2];
#pragma unroll
            for (int m = 0; m < 4; ++m) {
                const int lo = (m * 16 + lr) * H_STRIDE + t2 * 32 + kb * 8;
                ah[m] = *(const bf16x8*)&Hh[lo];
                al[m] = *(const bf16x8*)&Hl[lo];
            }
#pragma unroll
            for (int n = 0; n < 2; ++n) {
                int c = w * 2 + n;
                size_t boff = (size_t)((c * 8 + (h * 4 + t2)) * 64 + l) * 8;
                bh[n] = *(const bf16x8*)(B2h + boff);
                bl[n] = *(const bf16x8*)(B2l + boff);
            }
#pragma unroll
            for (int m = 0; m < 4; ++m)
#pragma unroll
                for (int n = 0; n < 2; ++n) {
                    acc2[m][n] = __builtin_amdgcn_mfma_f32_16x16x32_bf16(ah[m], bh[n], acc2[m][n], 0, 0, 0);
                    acc2[m][n] = __builtin_amdgcn_mfma_f32_16x16x32_bf16(al[m], bh[n], acc2[m][n], 0, 0, 0);
                    acc2[m][n] = __builtin_amdgcn_mfma_f32_16x16x32_bf16(ah[m], bl[n], acc2[m][n], 0, 0, 0);
                }
        }
    }

    // ---- epilogue
#pragma unroll
    for (int n = 0; n < 2; ++n) {
        int col = w * 32 + n * 16 + lr;
        float bb = b2[col];
#pragma unroll
        for (int m = 0; m < 4; ++m)
#pragma unroll
            for (int i = 0; i < 4; ++i) {
                size_t row = row0 + m * 16 + kb * 4 + i;
                float v = acc2[m][n][i] + bb;
                nhb[row * D_OUT + col] = f2bf(v);
                if ((int)row < Nvalid) out[row * D_OUT + col] = v;
            }
    }
}

// ---------------------------------------------------------------------------
// bucketing: histogram (returns in-bucket position), hierarchical scan, fill
// ---------------------------------------------------------------------------
__global__ __launch_bounds__(256)
void hist_pos(const int* __restrict__ dst, unsigned int* __restrict__ count,
              unsigned int* __restrict__ pos, int E)
{
    int e = blockIdx.x * blockDim.x + threadIdx.x;
    if (e < E) pos[e] = atomicAdd(count + dst[e], 1u);
}

__global__ __launch_bounds__(256)
void chunk_sums(const unsigned int* __restrict__ count,
                unsigned int* __restrict__ bsum, int n)
{
    __shared__ unsigned int lds[256];
    const int t = threadIdx.x;
    const int i = blockIdx.x * 256 + t;
    lds[t] = (i < n) ? count[i] : 0u;
    __syncthreads();
#pragma unroll
    for (int d = 128; d > 0; d >>= 1) {
        if (t < d) lds[t] += lds[t + d];
        __syncthreads();
    }
    if (t == 0) bsum[blockIdx.x] = lds[0];
}

// single block, nb <= 256
__global__ __launch_bounds__(256)
void scan_sums(const unsigned int* __restrict__ bsum,
               unsigned int* __restrict__ boff, int nb)
{
    __shared__ unsigned int lds[256];
    const int t = threadIdx.x;
    unsigned int v = (t < nb) ? bsum[t] : 0u;
    lds[t] = v;
    __syncthreads();
#pragma unroll
    for (int d = 1; d < 256; d <<= 1) {
        unsigned int x = lds[t];
        unsigned int add = (t >= d) ? lds[t - d] : 0u;
        __syncthreads();
        lds[t] = x + add;
        __syncthreads();
    }
    if (t < nb) boff[t] = lds[t] - v;     // exclusive
}

__global__ __launch_bounds__(256)
void write_off(const unsigned int* __restrict__ count,
               const unsigned int* __restrict__ boff,
               unsigned int* __restrict__ off, int n)
{
    __shared__ unsigned int lds[256];
    const int t = threadIdx.x;
    const int i = blockIdx.x * 256 + t;
    unsigned int v = (i < n) ? count[i] : 0u;
    lds[t] = v;
    __syncthreads();
#pragma unroll
    for (int d = 1; d < 256; d <<= 1) {
        unsigned int x = lds[t];
        unsigned int add = (t >= d) ? lds[t - d] : 0u;
        __syncthreads();
        lds[t] = x + add;
        __syncthreads();
    }
    unsigned int incl = lds[t];
    unsigned int base = boff[blockIdx.x];
    if (i < n)  off[i] = base + incl - v;
    if (i == n - 1) off[n] = base + incl;
}

__global__ __launch_bounds__(256)
void fill_srcs(const int* __restrict__ src, const int* __restrict__ dst,
               const unsigned int* __restrict__ off,
               const unsigned int* __restrict__ pos,
               int* __restrict__ srcs, int E)
{
    int e = blockIdx.x * blockDim.x + threadIdx.x;
    if (e >= E) return;
    srcs[off[dst[e]] + pos[e]] = src[e];
}

// ---------------------------------------------------------------------------
// One wave per dst node, 4x-unrolled online softmax over incident edges.
// ---------------------------------------------------------------------------
__device__ __forceinline__ float hi16f(unsigned int u) { return __uint_as_float(u << 16); }
__device__ __forceinline__ float lo16f(unsigned int u) { return __uint_as_float(u & 0xffff0000u); }

__global__ __launch_bounds__(256)
void node_aggregate(const short* __restrict__ nhb,
                    const unsigned int* __restrict__ off,
                    const int* __restrict__ srcs,
                    float* __restrict__ out, int N)
{
    int wid  = (blockIdx.x * blockDim.x + threadIdx.x) >> 6;
    int lane = threadIdx.x & 63;
    if (wid >= N) return;

    const unsigned int beg = off[wid];
    const unsigned int end = off[wid + 1];

    float2 self = *(const float2*)(out + (size_t)wid * D_OUT + lane * 2);

    float m = -INFINITY;
    float denom = 0.f, accx = 0.f, accy = 0.f;

    unsigned int i = beg;
    for (; i + 4 <= end; i += 4) {
        int s0 = srcs[i + 0], s1 = srcs[i + 1], s2 = srcs[i + 2], s3 = srcs[i + 3];
        unsigned int a0 = *(const unsigned int*)(nhb + (size_t)s0 * D_OUT + lane * 2);
        unsigned int a1 = *(const unsigned int*)(nhb + (size_t)s1 * D_OUT + lane * 2);
        unsigned int a2 = *(const unsigned int*)(nhb + (size_t)s2 * D_OUT + lane * 2);
        unsigned int a3 = *(const unsigned int*)(nhb + (size_t)s3 * D_OUT + lane * 2);
        float ax0 = hi16f(a0), ay0 = lo16f(a0);
        float ax1 = hi16f(a1), ay1 = lo16f(a1);
        float ax2 = hi16f(a2), ay2 = lo16f(a2);
        float ax3 = hi16f(a3), ay3 = lo16f(a3);
        float p0 = ax0 * self.x + ay0 * self.y;
        float p1 = ax1 * self.x + ay1 * self.y;
        float p2 = ax2 * self.x + ay2 * self.y;
        float p3 = ax3 * self.x + ay3 * self.y;
#pragma unroll
        for (int o = 32; o > 0; o >>= 1) {
            p0 += __shfl_xor(p0, o);
            p1 += __shfl_xor(p1, o);
            p2 += __shfl_xor(p2, o);
            p3 += __shfl_xor(p3, o);
        }
        float pm   = fmaxf(fmaxf(p0, p1), fmaxf(p2, p3));
        float mnew = fmaxf(m, pm);
        float scale = __expf(m - mnew);
        float w0 = __expf(p0 - mnew), w1 = __expf(p1 - mnew);
        float w2 = __expf(p2 - mnew), w3 = __expf(p3 - mnew);
        denom = denom * scale + ((w0 + w1) + (w2 + w3));
        accx  = accx  * scale + ((w0 * ax0 + w1 * ax1) + (w2 * ax2 + w3 * ax3));
        accy  = accy  * scale + ((w0 * ay0 + w1 * ay1) + (w2 * ay2 + w3 * ay3));
        m = mnew;
    }
    for (; i < end; ++i) {
        int s = srcs[i];
        unsigned int au = *(const unsigned int*)(nhb + (size_t)s * D_OUT + lane * 2);
        float ax = hi16f(au), ay = lo16f(au);
        float p = ax * self.x + ay * self.y;
#pragma unroll
        for (int o = 32; o > 0; o >>= 1) p += __shfl_xor(p, o);
        float mnew  = fmaxf(m, p);
        float scale = __expf(m - mnew);
        float wgt   = __expf(p - mnew);
        denom = denom * scale + wgt;
        accx  = accx * scale + wgt * ax;
        accy  = accy * scale + wgt * ay;
        m = mnew;
    }

    float inv = (denom > 0.f) ? 1.f / denom : 0.f;
    float2 o;
    o.x = self.x + accx * inv;
    o.y = self.y + accy * inv;
    *(float2*)(out + (size_t)wid * D_OUT + lane * 2) = o;
}

// ---------------------------------------------------------------------------
__global__ __launch_bounds__(256)
void copy_f4(const float4* __restrict__ in, float4* __restrict__ out, int n4)
{
    int i = blockIdx.x * blockDim.x + threadIdx.x;
    int stride = gridDim.x * blockDim.x;
    for (; i < n4; i += stride) out[i] = in[i];
}

// ---------------------------------------------------------------------------
extern "C" void kernel_launch(void* const* d_in, const int* in_sizes, int n_in,
                              void* d_out, int out_size, void* d_ws, size_t ws_size,
                              hipStream_t stream)
{
    const float* nh  = (const float*)d_in[0];
    const float* eh  = (const float*)d_in[1];
    const int*   ei  = (const int*)d_in[2];
    const float* W1  = (const float*)d_in[3];
    const float* b1  = (const float*)d_in[4];
    const float* W2  = (const float*)d_in[5];
    const float* b2  = (const float*)d_in[6];

    const int N  = in_sizes[0] / D_IN;        // 50000
    const int E  = in_sizes[2] / 2;           // 800000
    const int EH = in_sizes[1];               // E*16 floats
    const int Mp = (N + 63) & ~63;            // padded rows
    const int NB = (N + 255) / 256;           // scan chunks (196 <= 256)

    const int* src = ei;
    const int* dst = ei + E;

    float* out_nh = (float*)d_out;
    float* out_eh = (float*)d_out + (size_t)N * D_OUT;

    // workspace (~20 MB)
    char* ws = (char*)d_ws;
    size_t o = 0;
    short* nhb = (short*)(ws + o); o += (size_t)Mp * D_OUT * 2;
    short* B1h = (short*)(ws + o); o += (size_t)D_IN  * D_HID * 2;
    short* B1l = (short*)(ws + o); o += (size_t)D_IN  * D_HID * 2;
    short* B2h = (short*)(ws + o); o += (size_t)D_HID * D_OUT * 2;
    short* B2l = (short*)(ws + o); o += (size_t)D_HID * D_OUT * 2;
    int*          srcs  = (int*)(ws + o);          o += (size_t)E * 4;
    unsigned int* pos   = (unsigned int*)(ws + o); o += (size_t)E * 4;
    unsigned int* count = (unsigned int*)(ws + o); o += (size_t)N * 4;
    unsigned int* off   = (unsigned int*)(ws + o); o += (size_t)(N + 1) * 4;
    unsigned int* bsum  = (unsigned int*)(ws + o); o += (size_t)NB * 4;
    unsigned int* boff  = (unsigned int*)(ws + o); o += (size_t)NB * 4;

    // 1) weight packs (hi/lo)
    pack_w_split<<<16, 256, 0, stream>>>(W1, B1h, B1l, D_IN, D_HID);
    pack_w_split<<<16, 256, 0, stream>>>(W2, B2h, B2l, D_HID, D_OUT);

    // 2) bucket edges by dst (coalesced hierarchical scan)
    hipMemsetAsync(count, 0, (size_t)N * 4, stream);
    hist_pos<<<(E + 255) / 256, 256, 0, stream>>>(dst, count, pos, E);
    chunk_sums<<<NB, 256, 0, stream>>>(count, bsum, N);
    scan_sums<<<1, 256, 0, stream>>>(bsum, boff, NB);
    write_off<<<NB, 256, 0, stream>>>(count, boff, off, N);
    fill_srcs<<<(E + 255) / 256, 256, 0, stream>>>(src, dst, off, pos, srcs, E);

    // 3) fused MLP (split-bf16 MFMA, h1 in LDS)
    mlp_fused<<<Mp / 64, 256, 0, stream>>>(nh, B1h, B1l, b1, B2h, B2l, b2,
                                           out_nh, nhb, N);

    // 4) fused online-softmax aggregation, one wave per node
    node_aggregate<<<(N + 3) / 4, 256, 0, stream>>>(nhb, off, srcs, out_nh, N);

    // 5) eh passthrough
    copy_f4<<<2048, 256, 0, stream>>>((const float4*)eh, (float4*)out_eh, EH / 4);
}

// Round 7
// 175.139 us; speedup vs baseline: 5.8535x; 1.1489x over previous
//
#include <hip/hip_runtime.h>
#include <math.h>

// ---------------------------------------------------------------------------
// GAT layer. Split-bf16 MFMA MLP (A pre-split; h1 staged in LDS) + bucketed
// online-softmax aggregation (16-lane edge-groups, bf16x8 gathers).
//   n_h = relu(nh@W1+b1)@W2+b2
//   attn[e] = dot(n_h[src], n_h[dst]);  segment-softmax over dst
//   out0 = n_h + segsum(softmax * n_h[src]);  out1 = eh
// ---------------------------------------------------------------------------

#define D_IN   128
#define D_HID  256
#define D_OUT  128

typedef short bf16x8 __attribute__((ext_vector_type(8)));
typedef float f32x4  __attribute__((ext_vector_type(4)));

__device__ __forceinline__ short f2bf(float f)
{
    unsigned int u = __float_as_uint(f);
    unsigned int r = (u + 0x7fffu + ((u >> 16) & 1u)) >> 16;   // RNE
    return (short)r;
}
__device__ __forceinline__ float bf2f(short h)
{
    return __uint_as_float(((unsigned int)(unsigned short)h) << 16);
}

// ---------------------------------------------------------------------------
// pack W[K][N] fp32 into MFMA B-fragment hi/lo bf16 planes
// ---------------------------------------------------------------------------
__device__ __forceinline__ void pack_body(const float* __restrict__ W,
                                          short* __restrict__ Bh,
                                          short* __restrict__ Bl,
                                          int K, int N, int u)
{
    const int T = K >> 5;
    const int l = u & 63;
    const int t = (u >> 6) % T;
    const int c = u / (64 * T);
    const int lr = l & 15, kb = l >> 4;
    bf16x8 vh, vl;
#pragma unroll
    for (int j = 0; j < 8; ++j) {
        int k   = t * 32 + kb * 8 + j;
        int col = c * 16 + lr;
        float x = W[(size_t)k * N + col];
        short hi = f2bf(x);
        vh[j] = hi;
        vl[j] = f2bf(x - bf2f(hi));
    }
    *(bf16x8*)(Bh + (size_t)u * 8) = vh;
    *(bf16x8*)(Bl + (size_t)u * 8) = vl;
}

// ---------------------------------------------------------------------------
// prep: fused eh passthrough copy + A hi/lo split + both weight packs
// grid = COPY_BLOCKS + nAB + 32
// ---------------------------------------------------------------------------
#define PREP_COPY_BLOCKS 1024

__global__ __launch_bounds__(256)
void prep(const float* __restrict__ eh, float* __restrict__ out_eh, int n4,
          const float* __restrict__ A, short* __restrict__ Ah,
          short* __restrict__ Al, long valid, long total8, int nAB,
          const float* __restrict__ W1, short* __restrict__ B1h,
          short* __restrict__ B1l,
          const float* __restrict__ W2, short* __restrict__ B2h,
          short* __restrict__ B2l)
{
    int b = blockIdx.x;
    const int tid = threadIdx.x;
    if (b < PREP_COPY_BLOCKS) {                       // eh copy
        const float4* in4 = (const float4*)eh;
        float4* o4 = (float4*)out_eh;
        for (int i = b * 256 + tid; i < n4; i += PREP_COPY_BLOCKS * 256)
            o4[i] = in4[i];
        return;
    }
    b -= PREP_COPY_BLOCKS;
    if (b < nAB) {                                    // A split
        long t = (long)b * 256 + tid;
        if (t < total8) {
            long base = t * 8;
            bf16x8 vh, vl;
            if (base < valid) {
                float4 f0 = *(const float4*)(A + base);
                float4 f1 = *(const float4*)(A + base + 4);
                float fv[8] = {f0.x, f0.y, f0.z, f0.w, f1.x, f1.y, f1.z, f1.w};
#pragma unroll
                for (int j = 0; j < 8; ++j) {
                    short hi = f2bf(fv[j]);
                    vh[j] = hi;
                    vl[j] = f2bf(fv[j] - bf2f(hi));
                }
            } else {
                vh = (bf16x8)0; vl = (bf16x8)0;
            }
            *(bf16x8*)(Ah + base) = vh;
            *(bf16x8*)(Al + base) = vl;
        }
        return;
    }
    b -= nAB;                                         // weight packs (16+16)
    if (b < 16) pack_body(W1, B1h, B1l, D_IN, D_HID, b * 256 + tid);
    else        pack_body(W2, B2h, B2l, D_HID, D_OUT, (b - 16) * 256 + tid);
}

// ---------------------------------------------------------------------------
// Fused MLP: out/nhb = relu(A@W1+b1)@W2+b2, A pre-split bf16 hi/lo,
// h1 staged in LDS (hi/lo bf16), two 128-col halves. 4 waves, 64 rows/block.
// ---------------------------------------------------------------------------
#define H_STRIDE 136   // 128 + 8 bf16 pad (row offset = 4 banks)

__global__ __launch_bounds__(256)
void mlp_fused(const short* __restrict__ Ah, const short* __restrict__ Al,
               const short* __restrict__ B1h, const short* __restrict__ B1l,
               const float* __restrict__ b1,
               const short* __restrict__ B2h, const short* __restrict__ B2l,
               const float* __restrict__ b2,
               float* __restrict__ out, short* __restrict__ nhb, int Nvalid)
{
    __shared__ __attribute__((aligned(16))) short Hh[64 * H_STRIDE];
    __shared__ __attribute__((aligned(16))) short Hl[64 * H_STRIDE];

    const int w  = threadIdx.x >> 6;
    const int l  = threadIdx.x & 63;
    const int lr = l & 15, kb = l >> 4;
    const size_t row0 = (size_t)blockIdx.x * 64;

    f32x4 acc2[4][2] = {};

#pragma unroll
    for (int h = 0; h < 2; ++h) {
        // ---- GEMM1 for this col-half (pure bf16 loads, no split VALU)
        f32x4 acc1[4][2] = {};
#pragma unroll
        for (int t = 0; t < 4; ++t) {
            bf16x8 ah[4], al[4], bh[2], bl[2];
#pragma unroll
            for (int m = 0; m < 4; ++m) {
                size_t aoff = (row0 + m * 16 + lr) * D_IN + t * 32 + kb * 8;
                ah[m] = *(const bf16x8*)(Ah + aoff);
                al[m] = *(const bf16x8*)(Al + aoff);
            }
#pragma unroll
            for (int n = 0; n < 2; ++n) {
                int c = h * 8 + w * 2 + n;
                size_t boff = (size_t)((c * 4 + t) * 64 + l) * 8;
                bh[n] = *(const bf16x8*)(B1h + boff);
                bl[n] = *(const bf16x8*)(B1l + boff);
            }
#pragma unroll
            for (int m = 0; m < 4; ++m)
#pragma unroll
                for (int n = 0; n < 2; ++n) {
                    acc1[m][n] = __builtin_amdgcn_mfma_f32_16x16x32_bf16(ah[m], bh[n], acc1[m][n], 0, 0, 0);
                    acc1[m][n] = __builtin_amdgcn_mfma_f32_16x16x32_bf16(al[m], bh[n], acc1[m][n], 0, 0, 0);
                    acc1[m][n] = __builtin_amdgcn_mfma_f32_16x16x32_bf16(ah[m], bl[n], acc1[m][n], 0, 0, 0);
                }
        }
        // ---- bias + relu + split -> LDS
        if (h) __syncthreads();
#pragma unroll
        for (int n = 0; n < 2; ++n) {
            int lcol = w * 32 + n * 16 + lr;
            float bb = b1[h * 128 + lcol];
#pragma unroll
            for (int m = 0; m < 4; ++m)
#pragma unroll
                for (int i = 0; i < 4; ++i) {
                    int lrow = m * 16 + kb * 4 + i;
                    float v = fmaxf(acc1[m][n][i] + bb, 0.f);
                    short hi = f2bf(v);
                    Hh[lrow * H_STRIDE + lcol] = hi;
                    Hl[lrow * H_STRIDE + lcol] = f2bf(v - bf2f(hi));
                }
        }
        __syncthreads();

        // ---- GEMM2 partial accumulate over this half's K
#pragma unroll
        for (int t2 = 0; t2 < 4; ++t2) {
            bf16x8 ah[4], al[4], bh[2], bl[2];
#pragma unroll
            for (int m = 0; m < 4; ++m) {
                const int lo = (m * 16 + lr) * H_STRIDE + t2 * 32 + kb * 8;
                ah[m] = *(const bf16x8*)&Hh[lo];
                al[m] = *(const bf16x8*)&Hl[lo];
            }
#pragma unroll
            for (int n = 0; n < 2; ++n) {
                int c = w * 2 + n;
                size_t boff = (size_t)((c * 8 + (h * 4 + t2)) * 64 + l) * 8;
                bh[n] = *(const bf16x8*)(B2h + boff);
                bl[n] = *(const bf16x8*)(B2l + boff);
            }
#pragma unroll
            for (int m = 0; m < 4; ++m)
#pragma unroll
                for (int n = 0; n < 2; ++n) {
                    acc2[m][n] = __builtin_amdgcn_mfma_f32_16x16x32_bf16(ah[m], bh[n], acc2[m][n], 0, 0, 0);
                    acc2[m][n] = __builtin_amdgcn_mfma_f32_16x16x32_bf16(al[m], bh[n], acc2[m][n], 0, 0, 0);
                    acc2[m][n] = __builtin_amdgcn_mfma_f32_16x16x32_bf16(ah[m], bl[n], acc2[m][n], 0, 0, 0);
                }
        }
    }

    // ---- epilogue
#pragma unroll
    for (int n = 0; n < 2; ++n) {
        int col = w * 32 + n * 16 + lr;
        float bb = b2[col];
#pragma unroll
        for (int m = 0; m < 4; ++m)
#pragma unroll
            for (int i = 0; i < 4; ++i) {
                size_t row = row0 + m * 16 + kb * 4 + i;
                float v = acc2[m][n][i] + bb;
                nhb[row * D_OUT + col] = f2bf(v);
                if ((int)row < Nvalid) out[row * D_OUT + col] = v;
            }
    }
}

// ---------------------------------------------------------------------------
// bucketing: histogram (returns in-bucket position), hierarchical scan, fill
// ---------------------------------------------------------------------------
__global__ __launch_bounds__(256)
void hist_pos(const int* __restrict__ dst, unsigned int* __restrict__ count,
              unsigned int* __restrict__ pos, int E)
{
    int e = blockIdx.x * blockDim.x + threadIdx.x;
    if (e < E) pos[e] = atomicAdd(count + dst[e], 1u);
}

__global__ __launch_bounds__(256)
void chunk_sums(const unsigned int* __restrict__ count,
                unsigned int* __restrict__ bsum, int n)
{
    __shared__ unsigned int lds[256];
    const int t = threadIdx.x;
    const int i = blockIdx.x * 256 + t;
    lds[t] = (i < n) ? count[i] : 0u;
    __syncthreads();
#pragma unroll
    for (int d = 128; d > 0; d >>= 1) {
        if (t < d) lds[t] += lds[t + d];
        __syncthreads();
    }
    if (t == 0) bsum[blockIdx.x] = lds[0];
}

__global__ __launch_bounds__(256)
void scan_sums(const unsigned int* __restrict__ bsum,
               unsigned int* __restrict__ boff, int nb)
{
    __shared__ unsigned int lds[256];
    const int t = threadIdx.x;
    unsigned int v = (t < nb) ? bsum[t] : 0u;
    lds[t] = v;
    __syncthreads();
#pragma unroll
    for (int d = 1; d < 256; d <<= 1) {
        unsigned int x = lds[t];
        unsigned int add = (t >= d) ? lds[t - d] : 0u;
        __syncthreads();
        lds[t] = x + add;
        __syncthreads();
    }
    if (t < nb) boff[t] = lds[t] - v;     // exclusive
}

__global__ __launch_bounds__(256)
void write_off(const unsigned int* __restrict__ count,
               const unsigned int* __restrict__ boff,
               unsigned int* __restrict__ off, int n)
{
    __shared__ unsigned int lds[256];
    const int t = threadIdx.x;
    const int i = blockIdx.x * 256 + t;
    unsigned int v = (i < n) ? count[i] : 0u;
    lds[t] = v;
    __syncthreads();
#pragma unroll
    for (int d = 1; d < 256; d <<= 1) {
        unsigned int x = lds[t];
        unsigned int add = (t >= d) ? lds[t - d] : 0u;
        __syncthreads();
        lds[t] = x + add;
        __syncthreads();
    }
    unsigned int incl = lds[t];
    unsigned int base = boff[blockIdx.x];
    if (i < n)  off[i] = base + incl - v;
    if (i == n - 1) off[n] = base + incl;
}

__global__ __launch_bounds__(256)
void fill_srcs(const int* __restrict__ src, const int* __restrict__ dst,
               const unsigned int* __restrict__ off,
               const unsigned int* __restrict__ pos,
               int* __restrict__ srcs, int E)
{
    int e = blockIdx.x * blockDim.x + threadIdx.x;
    if (e >= E) return;
    srcs[off[dst[e]] + pos[e]] = src[e];
}

// ---------------------------------------------------------------------------
// One wave per dst node: 4 edge-groups x 16 lanes, online softmax.
// Lane j of each group holds dims [8j, 8j+8). bf16x8 gathers (16 B/lane).
// ---------------------------------------------------------------------------
#define NEG_HUGE -3.0e38f

__global__ __launch_bounds__(256)
void node_aggregate(const short* __restrict__ nhb,
                    const unsigned int* __restrict__ off,
                    const int* __restrict__ srcs,
                    float* __restrict__ out, int N)
{
    int wid  = (blockIdx.x * blockDim.x + threadIdx.x) >> 6;
    int lane = threadIdx.x & 63;
    if (wid >= N) return;
    const int g = lane >> 4;      // edge-group 0..3
    const int j = lane & 15;      // dim-lane

    const float* sp = out + (size_t)wid * D_OUT + j * 8;
    const float4 sa = *(const float4*)sp;
    const float4 sb = *(const float4*)(sp + 4);

    const unsigned int beg = off[wid];
    const unsigned int end = off[wid + 1];

    float m = NEG_HUGE, den = 0.f;
    float c0 = 0.f, c1 = 0.f, c2 = 0.f, c3 = 0.f;
    float c4 = 0.f, c5 = 0.f, c6 = 0.f, c7 = 0.f;

    for (unsigned int base = beg; base < end; base += 4) {
        unsigned int idx = base + g;
        bool valid = idx < end;
        int sidx = valid ? srcs[idx] : 0;
        uint4 av = *(const uint4*)(nhb + (size_t)sidx * D_OUT + j * 8);
        float a0 = __uint_as_float(av.x << 16);
        float a1 = __uint_as_float(av.x & 0xffff0000u);
        float a2 = __uint_as_float(av.y << 16);
        float a3 = __uint_as_float(av.y & 0xffff0000u);
        float a4 = __uint_as_float(av.z << 16);
        float a5 = __uint_as_float(av.z & 0xffff0000u);
        float a6 = __uint_as_float(av.w << 16);
        float a7 = __uint_as_float(av.w & 0xffff0000u);

        float p = a0 * sa.x + a1 * sa.y + a2 * sa.z + a3 * sa.w
                + a4 * sb.x + a5 * sb.y + a6 * sb.z + a7 * sb.w;
        p += __shfl_xor(p, 1);
        p += __shfl_xor(p, 2);
        p += __shfl_xor(p, 4);
        p += __shfl_xor(p, 8);

        float pv    = valid ? p : NEG_HUGE;
        float mnew  = fmaxf(m, pv);
        float scale = __expf(m - mnew);            // 0 on first valid step
        float wgt   = valid ? __expf(p - mnew) : 0.f;
        den = fmaf(den, scale, wgt);
        c0 = fmaf(c0, scale, wgt * a0);
        c1 = fmaf(c1, scale, wgt * a1);
        c2 = fmaf(c2, scale, wgt * a2);
        c3 = fmaf(c3, scale, wgt * a3);
        c4 = fmaf(c4, scale, wgt * a4);
        c5 = fmaf(c5, scale, wgt * a5);
        c6 = fmaf(c6, scale, wgt * a6);
        c7 = fmaf(c7, scale, wgt * a7);
        m = mnew;
    }

    // merge the 4 group states (flash-style)
#pragma unroll
    for (int o = 16; o < 64; o <<= 1) {
        float m2 = __shfl_xor(m, o);
        float d2 = __shfl_xor(den, o);
        float b0 = __shfl_xor(c0, o), b1 = __shfl_xor(c1, o);
        float b2v = __shfl_xor(c2, o), b3 = __shfl_xor(c3, o);
        float b4 = __shfl_xor(c4, o), b5 = __shfl_xor(c5, o);
        float b6 = __shfl_xor(c6, o), b7 = __shfl_xor(c7, o);
        float mn = fmaxf(m, m2);
        float s1 = __expf(m - mn);
        float s2 = __expf(m2 - mn);
        den = den * s1 + d2 * s2;
        c0 = c0 * s1 + b0 * s2;  c1 = c1 * s1 + b1 * s2;
        c2 = c2 * s1 + b2v * s2; c3 = c3 * s1 + b3 * s2;
        c4 = c4 * s1 + b4 * s2;  c5 = c5 * s1 + b5 * s2;
        c6 = c6 * s1 + b6 * s2;  c7 = c7 * s1 + b7 * s2;
        m = mn;
    }

    float inv = (den > 0.f) ? 1.f / den : 0.f;
    if (g == 0) {
        float4 o0, o1;
        o0.x = sa.x + c0 * inv; o0.y = sa.y + c1 * inv;
        o0.z = sa.z + c2 * inv; o0.w = sa.w + c3 * inv;
        o1.x = sb.x + c4 * inv; o1.y = sb.y + c5 * inv;
        o1.z = sb.z + c6 * inv; o1.w = sb.w + c7 * inv;
        float* op = out + (size_t)wid * D_OUT + j * 8;
        *(float4*)op = o0;
        *(float4*)(op + 4) = o1;
    }
}

// ---------------------------------------------------------------------------
extern "C" void kernel_launch(void* const* d_in, const int* in_sizes, int n_in,
                              void* d_out, int out_size, void* d_ws, size_t ws_size,
                              hipStream_t stream)
{
    const float* nh  = (const float*)d_in[0];
    const float* eh  = (const float*)d_in[1];
    const int*   ei  = (const int*)d_in[2];
    const float* W1  = (const float*)d_in[3];
    const float* b1  = (const float*)d_in[4];
    const float* W2  = (const float*)d_in[5];
    const float* b2  = (const float*)d_in[6];

    const int N  = in_sizes[0] / D_IN;        // 50000
    const int E  = in_sizes[2] / 2;           // 800000
    const int EH = in_sizes[1];               // E*16 floats
    const int Mp = (N + 63) & ~63;            // padded rows (50048)
    const int NB = (N + 255) / 256;           // scan chunks (196 <= 256)

    const int* src = ei;
    const int* dst = ei + E;

    float* out_nh = (float*)d_out;
    float* out_eh = (float*)d_out + (size_t)N * D_OUT;

    // workspace (~46 MB)
    char* ws = (char*)d_ws;
    size_t o = 0;
    short* Ahp = (short*)(ws + o); o += (size_t)Mp * D_IN * 2;
    short* Alp = (short*)(ws + o); o += (size_t)Mp * D_IN * 2;
    short* nhb = (short*)(ws + o); o += (size_t)Mp * D_OUT * 2;
    short* B1h = (short*)(ws + o); o += (size_t)D_IN  * D_HID * 2;
    short* B1l = (short*)(ws + o); o += (size_t)D_IN  * D_HID * 2;
    short* B2h = (short*)(ws + o); o += (size_t)D_HID * D_OUT * 2;
    short* B2l = (short*)(ws + o); o += (size_t)D_HID * D_OUT * 2;
    int*          srcs  = (int*)(ws + o);          o += (size_t)E * 4;
    unsigned int* pos   = (unsigned int*)(ws + o); o += (size_t)E * 4;
    unsigned int* count = (unsigned int*)(ws + o); o += (size_t)N * 4;
    unsigned int* off   = (unsigned int*)(ws + o); o += (size_t)(N + 1) * 4;
    unsigned int* bsum  = (unsigned int*)(ws + o); o += (size_t)NB * 4;
    unsigned int* boff  = (unsigned int*)(ws + o); o += (size_t)NB * 4;

    // 1) prep: eh copy + A hi/lo split + weight packs (one kernel)
    {
        long total8 = (long)Mp * D_IN / 8;
        int  nAB    = (int)((total8 + 255) / 256);
        prep<<<PREP_COPY_BLOCKS + nAB + 32, 256, 0, stream>>>(
            eh, out_eh, EH / 4,
            nh, Ahp, Alp, (long)N * D_IN, total8, nAB,
            W1, B1h, B1l, W2, B2h, B2l);
    }

    // 2) bucket edges by dst
    hipMemsetAsync(count, 0, (size_t)N * 4, stream);
    hist_pos<<<(E + 255) / 256, 256, 0, stream>>>(dst, count, pos, E);
    chunk_sums<<<NB, 256, 0, stream>>>(count, bsum, N);
    scan_sums<<<1, 256, 0, stream>>>(bsum, boff, NB);
    write_off<<<NB, 256, 0, stream>>>(count, boff, off, N);
    fill_srcs<<<(E + 255) / 256, 256, 0, stream>>>(src, dst, off, pos, srcs, E);

    // 3) fused MLP (split-bf16 MFMA, h1 in LDS)
    mlp_fused<<<Mp / 64, 256, 0, stream>>>(Ahp, Alp, B1h, B1l, b1,
                                           B2h, B2l, b2, out_nh, nhb, N);

    // 4) fused online-softmax aggregation, one wave per node
    node_aggregate<<<(N + 3) / 4, 256, 0, stream>>>(nhb, off, srcs, out_nh, N);
}